// Round 7
// baseline (40.636 us; speedup 1.0000x reference)
//
#include <hip/hip_runtime.h>
#include <math.h>

// Problem constants (B=8, N=M=4096, D=2)
#define NPTS 4096
#define G    64
#define NC   (G * G)   // 4096 cells, row-major j*G+i

__device__ __forceinline__ float scan_pts(const float2* __restrict__ p, int s, int e,
                                          float qx, float qy, float best)
{
    for (int k = s; k < e; ++k) {
        const float2 pt = p[k];
        const float dx = qx - pt.x, dy = qy - pt.y;
        best = fminf(best, fmaf(dx, dx, dy * dy));
    }
    return best;
}

// 256 blocks = 16 sides x 16 query-tiles; 1024 threads = 256 queries x 4 lanes.
// Each block: counting-sort its side's 4096 stream pts into an LDS grid, then
// exact NN per query (4-lane split 3x3 scan + rare ring expansion on lane 0).
__global__ __launch_bounds__(1024) void chamfer_fused(
    const float* __restrict__ x, const float* __restrict__ tgt,
    float* __restrict__ partials)
{
    __shared__ float2 spts[NPTS];              // 32 KB cell-sorted stream points
    __shared__ unsigned int counts[NC];        // 16 KB hist -> cursors -> reduce buf
    __shared__ unsigned short sstart[NC + 2];  // 8.2 KB cell starts + sentinel
    __shared__ float misc[64];                 // bbox wave partials (16 waves x 4)
    __shared__ int wtot[16];

    const int bid  = blockIdx.x;
    const int side = bid >> 4, tile = bid & 15;
    const int b    = side & 7;
    const int t    = threadIdx.x, lane = t & 63, w = t >> 6;

    const float* sarr = (side < 8) ? tgt : x;   // stream (binned) points
    const float* qarr = (side < 8) ? x   : tgt; // query points

    // ---- load stream points: 2 float4 = 4 points per thread (coalesced) ----
    const float4* sp4g = (const float4*)(sarr + b * (NPTS * 2));
    const float4 pka = sp4g[t];
    const float4 pkb = sp4g[t + 1024];
    // my query: 4 consecutive lanes share one query (same-addr broadcast load)
    const int qi = t >> 2, ql = t & 3;
    const float2 q = ((const float2*)(qarr + b * (NPTS * 2)))[tile * 256 + qi];

    // zero histogram
    #pragma unroll
    for (int k = 0; k < NC / 1024; ++k) counts[k * 1024 + t] = 0u;

    // ---- exact stream bbox ----
    float mnx = fminf(fminf(pka.x, pka.z), fminf(pkb.x, pkb.z));
    float mxx = fmaxf(fmaxf(pka.x, pka.z), fmaxf(pkb.x, pkb.z));
    float mny = fminf(fminf(pka.y, pka.w), fminf(pkb.y, pkb.w));
    float mxy = fmaxf(fmaxf(pka.y, pka.w), fmaxf(pkb.y, pkb.w));
    for (int off = 32; off; off >>= 1) {
        mnx = fminf(mnx, __shfl_down(mnx, off));
        mxx = fmaxf(mxx, __shfl_down(mxx, off));
        mny = fminf(mny, __shfl_down(mny, off));
        mxy = fmaxf(mxy, __shfl_down(mxy, off));
    }
    if (lane == 0) { misc[w] = mnx; misc[16 + w] = mxx; misc[32 + w] = mny; misc[48 + w] = mxy; }
    __syncthreads();
    float x0 = INFINITY, x1 = -INFINITY, y0 = INFINITY, y1 = -INFINITY;
    #pragma unroll
    for (int k = 0; k < 16; ++k) {       // same-addr broadcast reads
        x0 = fminf(x0, misc[k]);      x1 = fmaxf(x1, misc[16 + k]);
        y0 = fminf(y0, misc[32 + k]); y1 = fmaxf(y1, misc[48 + k]);
    }
    const float invx = (float)G / (x1 - x0), invy = (float)G / (y1 - y0);
    const float cwx = (x1 - x0) * (1.0f / G), cwy = (y1 - y0) * (1.0f / G);

    // ---- histogram (4 cells/thread) ----
    int cell[4];
    {
        int ci0 = (int)((pka.x - x0) * invx); ci0 = ci0 < 0 ? 0 : (ci0 > G-1 ? G-1 : ci0);
        int cj0 = (int)((pka.y - y0) * invy); cj0 = cj0 < 0 ? 0 : (cj0 > G-1 ? G-1 : cj0);
        int ci1 = (int)((pka.z - x0) * invx); ci1 = ci1 < 0 ? 0 : (ci1 > G-1 ? G-1 : ci1);
        int cj1 = (int)((pka.w - y0) * invy); cj1 = cj1 < 0 ? 0 : (cj1 > G-1 ? G-1 : cj1);
        int ci2 = (int)((pkb.x - x0) * invx); ci2 = ci2 < 0 ? 0 : (ci2 > G-1 ? G-1 : ci2);
        int cj2 = (int)((pkb.y - y0) * invy); cj2 = cj2 < 0 ? 0 : (cj2 > G-1 ? G-1 : cj2);
        int ci3 = (int)((pkb.z - x0) * invx); ci3 = ci3 < 0 ? 0 : (ci3 > G-1 ? G-1 : ci3);
        int cj3 = (int)((pkb.w - y0) * invy); cj3 = cj3 < 0 ? 0 : (cj3 > G-1 ? G-1 : cj3);
        cell[0] = cj0 * G + ci0; cell[1] = cj1 * G + ci1;
        cell[2] = cj2 * G + ci2; cell[3] = cj3 * G + ci3;
    }
    #pragma unroll
    for (int k = 0; k < 4; ++k) atomicAdd(&counts[cell[k]], 1u);
    __syncthreads();

    // ---- exclusive scan of 4096 counts (4/thread, 16-wave combine) ----
    const int base = t * 4;
    const unsigned int c0 = counts[base], c1 = counts[base + 1];
    const unsigned int c2 = counts[base + 2], c3 = counts[base + 3];
    const unsigned int run = c0 + c1 + c2 + c3;
    int v = (int)run;
    for (int off = 1; off < 64; off <<= 1) {
        int u = __shfl_up(v, off);
        if (lane >= off) v += u;
    }
    if (lane == 63) wtot[w] = v;
    __syncthreads();
    int wbase = 0;
    #pragma unroll
    for (int ww = 0; ww < 16; ++ww) wbase += (ww < w) ? wtot[ww] : 0;
    unsigned int st = (unsigned int)(wbase + v) - run;
    sstart[base]     = (unsigned short)st; counts[base]     = st; st += c0;
    sstart[base + 1] = (unsigned short)st; counts[base + 1] = st; st += c1;
    sstart[base + 2] = (unsigned short)st; counts[base + 2] = st; st += c2;
    sstart[base + 3] = (unsigned short)st; counts[base + 3] = st;
    if (t == 0) sstart[NC] = (unsigned short)NPTS;  // sentinel
    __syncthreads();

    // ---- scatter (order within cell irrelevant: fmin downstream) ----
    {
        unsigned int pos;
        pos = atomicAdd(&counts[cell[0]], 1u); spts[pos] = make_float2(pka.x, pka.y);
        pos = atomicAdd(&counts[cell[1]], 1u); spts[pos] = make_float2(pka.z, pka.w);
        pos = atomicAdd(&counts[cell[2]], 1u); spts[pos] = make_float2(pkb.x, pkb.y);
        pos = atomicAdd(&counts[cell[3]], 1u); spts[pos] = make_float2(pkb.z, pkb.w);
    }
    __syncthreads();

    // ---- search: 4 lanes split the 3x3 neighborhood scan ----
    const float gxf = (q.x - x0) * invx, gyf = (q.y - y0) * invy;
    int ci = (int)floorf(gxf); ci = ci < 0 ? 0 : (ci > G-1 ? G-1 : ci);
    int cj = (int)floorf(gyf); cj = cj < 0 ? 0 : (cj > G-1 ? G-1 : cj);
    // fx,fy relative to clamped cell: bound below stays exact even out-of-bbox
    const float fx = gxf - (float)ci, fy = gyf - (float)cj;

    const int ilo = ci - 1 < 0 ? 0 : ci - 1;
    const int ihi = ci + 1 > G-1 ? G-1 : ci + 1;
    const int jt  = cj - 1 < 0 ? 0 : cj - 1;
    const int jb  = cj + 1 > G-1 ? G-1 : cj + 1;

    int rs0, re0, rs1 = 0, re1 = 0, rs2 = 0, re2 = 0;   // static (no scratch)
    rs0 = sstart[jt * G + ilo]; re0 = sstart[jt * G + ihi + 1];
    if (jt + 1 <= jb) { rs1 = sstart[(jt+1) * G + ilo]; re1 = sstart[(jt+1) * G + ihi + 1]; }
    if (jt + 2 <= jb) { rs2 = sstart[(jt+2) * G + ilo]; re2 = sstart[(jt+2) * G + ihi + 1]; }
    const int l0 = re0 - rs0, l1 = re1 - rs1, l2 = re2 - rs2;
    const int L = l0 + l1 + l2;
    const int a  = (L * ql) >> 2;        // this lane's slice of the 3 ranges
    const int bq = (L * (ql + 1)) >> 2;

    float best = INFINITY;
    {
        int lo = a, hi = bq > l0 ? l0 : bq;
        if (lo < hi) best = scan_pts(spts, rs0 + lo, rs0 + hi, q.x, q.y, best);
    }
    {
        int lo = a - l0, hi = bq - l0;
        lo = lo < 0 ? 0 : lo; hi = hi > l1 ? l1 : hi;
        if (lo < hi) best = scan_pts(spts, rs1 + lo, rs1 + hi, q.x, q.y, best);
    }
    {
        int lo = a - l0 - l1, hi = bq - l0 - l1;
        lo = lo < 0 ? 0 : lo; hi = hi > l2 ? l2 : hi;
        if (lo < hi) best = scan_pts(spts, rs2 + lo, rs2 + hi, q.x, q.y, best);
    }
    // combine the 4 lanes of this query
    best = fminf(best, __shfl_xor(best, 1));
    best = fminf(best, __shfl_xor(best, 2));

    // ---- rare ring expansion (exact, masked lower bound) on lane 0 ----
    if (ql == 0) {
        for (int r = 2; r <= G; ++r) {
            const bool hasL = (ci - r >= 0), hasR = (ci + r <= G-1);
            const bool hasT = (cj - r >= 0), hasB = (cj + r <= G-1);
            float bnd = INFINITY;
            if (hasL) bnd = fminf(bnd, ((float)(r-1) + fx) * cwx);
            if (hasR) bnd = fminf(bnd, ((float)r - fx) * cwx);
            if (hasT) bnd = fminf(bnd, ((float)(r-1) + fy) * cwy);
            if (hasB) bnd = fminf(bnd, ((float)r - fy) * cwy);
            if (bnd * bnd >= best) break;   // covers ring-exhausted (bnd=INF)

            const int rlo = ci - r < 0 ? 0 : ci - r;
            const int rhi = ci + r > G-1 ? G-1 : ci + r;
            if (hasT) {
                const int ro = (cj - r) * G;
                best = scan_pts(spts, sstart[ro + rlo], sstart[ro + rhi + 1], q.x, q.y, best);
            }
            if (hasB) {
                const int ro = (cj + r) * G;
                best = scan_pts(spts, sstart[ro + rlo], sstart[ro + rhi + 1], q.x, q.y, best);
            }
            const int jlo = cj - r + 1 < 0 ? 0 : cj - r + 1;
            const int jhi = cj + r - 1 > G-1 ? G-1 : cj + r - 1;
            if (hasL) {
                const int col = ci - r;
                for (int j = jlo; j <= jhi; ++j) {
                    const int c = j * G + col;
                    best = scan_pts(spts, sstart[c], sstart[c + 1], q.x, q.y, best);
                }
            }
            if (hasR) {
                const int col = ci + r;
                for (int j = jlo; j <= jhi; ++j) {
                    const int c = j * G + col;
                    best = scan_pts(spts, sstart[c], sstart[c + 1], q.x, q.y, best);
                }
            }
        }
    }

    // ---- block sum of sqrt(best) -> partials ----
    float* red = (float*)counts;   // counts no longer needed
    if (ql == 0) red[qi] = sqrtf(fmaxf(best, 0.f));
    __syncthreads();
    if (t < 64) {
        float s = red[t] + red[t + 64] + red[t + 128] + red[t + 192];
        s += __shfl_down(s, 32);
        s += __shfl_down(s, 16);
        s += __shfl_down(s, 8);
        s += __shfl_down(s, 4);
        s += __shfl_down(s, 2);
        s += __shfl_down(s, 1);
        if (t == 0) partials[bid] = s;
    }
}

__global__ __launch_bounds__(256) void chamfer_final(
    const float* __restrict__ partials, float* __restrict__ out)
{
    __shared__ float red[256];
    const int tid = threadIdx.x;
    red[tid] = partials[tid];
    __syncthreads();
    if (tid < 64) {
        float v = red[tid] + red[tid + 64] + red[tid + 128] + red[tid + 192];
        v += __shfl_down(v, 32);
        v += __shfl_down(v, 16);
        v += __shfl_down(v, 8);
        v += __shfl_down(v, 4);
        v += __shfl_down(v, 2);
        v += __shfl_down(v, 1);
        // mean(d_t_to_x) + mean(d_x_to_t): both divide by B*4096 = 32768
        if (tid == 0) out[0] = v * (1.0f / 32768.0f);
    }
}

extern "C" void kernel_launch(void* const* d_in, const int* in_sizes, int n_in,
                              void* d_out, int out_size, void* d_ws, size_t ws_size,
                              hipStream_t stream) {
    const float* x   = (const float*)d_in[0];
    const float* tgt = (const float*)d_in[1];
    float* partials  = (float*)d_ws;   // 256 floats
    float* out       = (float*)d_out;  // 1 float

    chamfer_fused<<<dim3(256), dim3(1024), 0, stream>>>(x, tgt, partials);
    chamfer_final<<<dim3(1),   dim3(256), 0, stream>>>(partials, out);
}

// Round 8
// 26.238 us; speedup vs baseline: 1.5488x; 1.5488x over previous
//
#include <hip/hip_runtime.h>
#include <math.h>

// Problem constants (B=8, N=M=4096, D=2)
#define NPTS  4096
#define BQ    64      // queries per block
#define RQ    16      // queries per thread
#define SLOTS 4       // BQ/RQ threads span the query tile
#define NS    128     // chunk groups (512 threads / SLOTS)
#define CHUNK 32      // NPTS/NS stream points per chunk
#define CF4   16      // CHUNK/2 float4 per chunk
#define PCF4  17      // padded chunk stride: bank = 4*(s+j)%32 -> 2-way (free)

// grid 1024 = 2 dirs x 8 batches x 64 query-tiles; 512 thr; 4 blocks/CU.
__global__ __launch_bounds__(512, 6) void chamfer_main(
    const float* __restrict__ x, const float* __restrict__ tgt,
    float* __restrict__ partials)
{
    __shared__ float4 sm[NS * PCF4];   // 2176 float4 = 34.8 KB (padded)
    __shared__ float  red[8 * BQ];     // 2 KB cross-wave partial mins

    const int bx  = blockIdx.x;
    const int dir = bx >> 9;           // 0: queries=x stream=target, 1: swapped
    const int b   = (bx >> 6) & 7;
    const int qt  = bx & 63;           // 64 query tiles of 64
    const int t   = threadIdx.x;
    const int lane = t & 63, w = t >> 6;

    const float* qarr = dir ? tgt : x;
    const float* sarr = dir ? x   : tgt;

    // ---- stage stream points, padded layout: idx -> idx + idx/16 ----
    const float4* sp4 = (const float4*)(sarr + b * (NPTS * 2));
    #pragma unroll
    for (int k = 0; k < 4; ++k) {
        const int i = t + k * 512;
        sm[i + (i >> 4)] = sp4[i];
    }

    // ---- per-thread query setup: RQ=16 queries in registers ----
    const int slot = t & (SLOTS - 1);
    const int s    = t >> 2;           // chunk id 0..127
    const float2* qp = (const float2*)(qarr + b * (NPTS * 2));
    float nx[RQ], ny[RQ], m[RQ];
    #pragma unroll
    for (int r = 0; r < RQ; ++r) {
        const float2 p = qp[qt * BQ + slot + SLOTS * r];
        nx[r] = -2.f * p.x;
        ny[r] = -2.f * p.y;
        m[r]  = INFINITY;
    }
    __syncthreads();

    // ---- inner loop: 1 ds_read_b128 (2 pts) -> 82 VALU; conflict-free ----
    const float4* tp = sm + s * PCF4;
    #pragma unroll 4
    for (int j = 0; j < CF4; ++j) {
        const float4 t4 = tp[j];
        const float z0 = fmaf(t4.x, t4.x, t4.y * t4.y);
        const float z1 = fmaf(t4.z, t4.z, t4.w * t4.w);
        #pragma unroll
        for (int r = 0; r < RQ; ++r) {
            const float d0 = fmaf(nx[r], t4.x, fmaf(ny[r], t4.y, z0));
            const float d1 = fmaf(nx[r], t4.z, fmaf(ny[r], t4.w, z1));
            m[r] = fminf(fminf(m[r], d0), d1);   // -> v_min3_f32
        }
    }

    // fold query norm (min(m)+pp == min(m+pp), pp constant per query)
    #pragma unroll
    for (int r = 0; r < RQ; ++r)
        m[r] += 0.25f * fmaf(nx[r], nx[r], ny[r] * ny[r]);

    // ---- intra-wave reduce across the 16 s-groups (lane bits 2..5) ----
    #pragma unroll
    for (int r = 0; r < RQ; ++r) {
        m[r] = fminf(m[r], __shfl_xor(m[r], 4));
        m[r] = fminf(m[r], __shfl_xor(m[r], 8));
        m[r] = fminf(m[r], __shfl_xor(m[r], 16));
        m[r] = fminf(m[r], __shfl_xor(m[r], 32));
    }
    if (lane < SLOTS) {
        #pragma unroll
        for (int r = 0; r < RQ; ++r) red[w * BQ + lane + SLOTS * r] = m[r];
    }
    __syncthreads();

    // ---- cross-wave min (8 waves) + sqrt + block sum (wave 0) ----
    if (t < BQ) {
        float mm = red[t];
        #pragma unroll
        for (int ww = 1; ww < 8; ++ww) mm = fminf(mm, red[ww * BQ + t]);
        float v = sqrtf(fmaxf(mm, 0.f));
        v += __shfl_down(v, 32);
        v += __shfl_down(v, 16);
        v += __shfl_down(v, 8);
        v += __shfl_down(v, 4);
        v += __shfl_down(v, 2);
        v += __shfl_down(v, 1);
        if (t == 0) partials[bx] = v;
    }
}

__global__ __launch_bounds__(256) void chamfer_final(
    const float* __restrict__ partials, float* __restrict__ out)
{
    __shared__ float red[256];
    const int tid = threadIdx.x;
    float v = partials[tid] + partials[tid + 256] +
              partials[tid + 512] + partials[tid + 768];
    red[tid] = v;
    __syncthreads();
    if (tid < 64) {
        float s = red[tid] + red[tid + 64] + red[tid + 128] + red[tid + 192];
        s += __shfl_down(s, 32);
        s += __shfl_down(s, 16);
        s += __shfl_down(s, 8);
        s += __shfl_down(s, 4);
        s += __shfl_down(s, 2);
        s += __shfl_down(s, 1);
        // mean(d_t_to_x) + mean(d_x_to_t): both halves divide by B*4096 = 32768
        if (tid == 0) out[0] = s * (1.0f / 32768.0f);
    }
}

extern "C" void kernel_launch(void* const* d_in, const int* in_sizes, int n_in,
                              void* d_out, int out_size, void* d_ws, size_t ws_size,
                              hipStream_t stream) {
    const float* x   = (const float*)d_in[0];
    const float* tgt = (const float*)d_in[1];
    float* partials  = (float*)d_ws;   // 1024 floats
    float* out       = (float*)d_out;  // 1 float

    chamfer_main<<<dim3(1024), dim3(512), 0, stream>>>(x, tgt, partials);
    chamfer_final<<<dim3(1),   dim3(256), 0, stream>>>(partials, out);
}